// Round 6
// baseline (93.915 us; speedup 1.0000x reference)
//
#include <hip/hip_runtime.h>
#include <cmath>

#define LSEQ   1024
#define NPROJ  4620
#define NPADW  4736
#define DINNER 1536
#define NH     12
#define HDIM   128
#define OFF_Z  0
#define OFF_X  1536
#define OFF_B  3072
#define OFF_C  3840
#define OFF_DT 4608

typedef unsigned short u16;
typedef short bf16x8 __attribute__((ext_vector_type(8)));
typedef float f32x4 __attribute__((ext_vector_type(4)));

__device__ inline u16 f2b(float f) {            // f32 -> bf16 RNE
  unsigned u = __float_as_uint(f);
  return (u16)((u + 0x7fffu + ((u >> 16) & 1u)) >> 16);
}

__device__ inline void gll16(const void* g, void* l) {
  __builtin_amdgcn_global_load_lds((const __attribute__((address_space(1))) void*)g,
                                   (__attribute__((address_space(3))) void*)l, 16, 0, 0);
}

// ---------- split to single bf16 planes: x -> Ah, W_in -> Wh (padded), W_out -> Woh ----
#define S0N 196608              // 1024*768/4
#define S1N 909312              // 4736*768/4 (valid 887040)
#define S1V 887040
#define S2N 294912              // 768*1536/4
__global__ __launch_bounds__(256) void ksplit_all(const float* __restrict__ x,
    const float* __restrict__ Wi, const float* __restrict__ Wo,
    u16* __restrict__ Ah, u16* __restrict__ Wh, u16* __restrict__ Woh) {
  int i = blockIdx.x * 256 + threadIdx.x;
  const float* src; u16* hi; int j, valid;
  if (i < S0N)            { src = x;  hi = Ah;  j = i;              valid = S0N; }
  else if (i < S0N + S1N) { src = Wi; hi = Wh;  j = i - S0N;        valid = S1V; }
  else                    { src = Wo; hi = Woh; j = i - S0N - S1N;  valid = S2N; }
  float4 v = (j < valid) ? ((const float4*)src)[j] : make_float4(0.f, 0.f, 0.f, 0.f);
  u16 h[4] = {f2b(v.x), f2b(v.y), f2b(v.z), f2b(v.w)};
  uint2 hp;
  hp.x = (unsigned)h[0] | ((unsigned)h[1] << 16);
  hp.y = (unsigned)h[2] | ((unsigned)h[3] << 16);
  ((uint2*)hi)[j] = hp;
}

// ---------- pure-bf16 MFMA GEMM: C = A[M,K] * W[N,K]^T ----------
// BK=64, single LDS buffer, 256 thr (4 waves 2x2). R5-proven loop structure:
// ds_read frags -> barrier -> stage(t+1) (flies under MFMA) -> MFMA -> vmcnt(0)+barrier.
template<int BM, int BN, int MAP, bool NG>
__global__ __launch_bounds__(256) void gemm1(const u16* __restrict__ Ah,
    const u16* __restrict__ Wh, float* __restrict__ C,
    int lda, int ldw, int Ksl, int Nreal, int ldc) {
  constexpr int PLA = BM * 64;          // u16 in A region
  constexpr int IA = BM / 8, IW = BN / 8, ITOT = IA + IW;
  constexpr int FRn = BN / 32;
  __shared__ u16 lds[PLA + BN * 64];
  const int tid = threadIdx.x;
  const int l = tid & 63, w = tid >> 6;
  const int wm = w >> 1, wn = w & 1;
  const int kg = l >> 4, li = l & 15;

  int b = blockIdx.x, m0, n0, koff;
  float* Cp = C;
  if (MAP == 0) {                 // in-proj: 8 xcd * (5 colblk(128) x 16 rowblk(64))
    int xcd = b & 7, idx = b >> 3;
    m0 = (idx & 15) * 64;
    n0 = (xcd * 5 + (idx >> 4)) * 128;
    koff = 0;
    if (NG && n0 >= NPADW) return;      // fully-dead padded col-blocks
  } else {                        // out-proj: split-K=4; 8 xcd * (6 grp x 16 rowblk)
    int xcd = b & 7, idx = b >> 3;
    int gg = xcd * 6 + (idx >> 4);      // 0..47 = (n 0..11, kslice 0..3)
    m0 = (idx & 15) * 64;
    n0 = (gg % 12) * 64;
    koff = (gg / 12) * 384;
    Cp = C + (size_t)(gg / 12) * LSEQ * ldc;
  }

  const int srcg = ((l & 7) ^ (l >> 3)) * 8;   // pre-swizzled source granule (rule 21)
  auto stage = [&](int t) {
    const int k0 = koff + t * 64;
    for (int q = w; q < ITOT; q += 4) {
      const u16* gb; int r0b, ldk, dst;
      if (q < IA) { gb = Ah; r0b = m0 + 8 * q;        dst = 8 * q * 64;              ldk = lda; }
      else        { gb = Wh; r0b = n0 + 8 * (q - IA); dst = PLA + 8 * (q - IA) * 64; ldk = ldw; }
      gll16(gb + (size_t)(r0b + (l >> 3)) * ldk + k0 + srcg, &lds[dst]);
    }
  };
  auto rd = [&](int region, int row, int ks) -> bf16x8 {
    return *(const bf16x8*)&lds[region + row * 64 + (((ks * 4 + kg) ^ (row & 7)) << 3)];
  };

  f32x4 acc[2][FRn];
#pragma unroll
  for (int m = 0; m < 2; ++m)
#pragma unroll
    for (int n = 0; n < FRn; ++n) acc[m][n] = (f32x4){0.f, 0.f, 0.f, 0.f};

  const int NT = Ksl / 64;
  stage(0);
  asm volatile("s_waitcnt vmcnt(0)" ::: "memory");
  __syncthreads();
  for (int t = 0; t < NT; ++t) {
    bf16x8 af[2][2], wf[FRn][2];
#pragma unroll
    for (int ks = 0; ks < 2; ++ks) {
#pragma unroll
      for (int m = 0; m < 2; ++m)
        af[m][ks] = rd(0, wm * 32 + m * 16 + li, ks);
#pragma unroll
      for (int n = 0; n < FRn; ++n)
        wf[n][ks] = rd(PLA, wn * (BN / 2) + n * 16 + li, ks);
    }
    __syncthreads();                    // lgkm drained: regs valid, LDS free
    if (t + 1 < NT) stage(t + 1);       // loads fly under the MFMA block
#pragma unroll
    for (int ks = 0; ks < 2; ++ks)
#pragma unroll
      for (int m = 0; m < 2; ++m)
#pragma unroll
        for (int n = 0; n < FRn; ++n)
          acc[m][n] = __builtin_amdgcn_mfma_f32_16x16x32_bf16(af[m][ks], wf[n][ks], acc[m][n], 0, 0, 0);
    if (t + 1 < NT) {
      asm volatile("s_waitcnt vmcnt(0)" ::: "memory");
      __syncthreads();
    }
  }
#pragma unroll
  for (int m = 0; m < 2; ++m) {
    int rbase = m0 + wm * 32 + m * 16 + kg * 4;
#pragma unroll
    for (int n = 0; n < FRn; ++n) {
      int col = n0 + wn * (BN / 2) + n * 16 + li;
      if (!NG || col < Nreal) {
#pragma unroll
        for (int r = 0; r < 4; ++r)
          Cp[(size_t)(rbase + r) * ldc + col] = acc[m][n][r];
      }
    }
  }
}

// ---------------- out = P0+P1+P2+P3 (split-K reduce) ----------------
__global__ __launch_bounds__(256) void addk(const float* __restrict__ P,
    float* __restrict__ out) {
  const int S = LSEQ * 768 / 4;
  int i = blockIdx.x * 256 + threadIdx.x;
  float4 a = ((const float4*)P)[i];
  float4 b = ((const float4*)P)[i + S];
  float4 c = ((const float4*)P)[i + 2 * S];
  float4 d = ((const float4*)P)[i + 3 * S];
  ((float4*)out)[i] = make_float4(a.x + b.x + c.x + d.x, a.y + b.y + c.y + d.y,
                                  a.z + b.z + c.z + d.z, a.w + b.w + c.w + d.w);
}

// ---------------- dt = softplus(dt_r)+bias ; Phi = cumsum(A*dt) --------------
__global__ __launch_bounds__(256) void dtphi(const float* __restrict__ proj,
    const float* __restrict__ A_log, const float* __restrict__ dt_bias,
    float* __restrict__ Phi, float* __restrict__ dts) {
  int h = blockIdx.x, tid = threadIdx.x;
  float Ac = -expf(A_log[h]);
  float bb = dt_bias[h];
  float v[4], s = 0.f;
#pragma unroll
  for (int u = 0; u < 4; ++u) {
    int t = tid * 4 + u;
    float xr = proj[(size_t)t * NPROJ + OFF_DT + h];
    float sp = (xr > 20.f) ? xr : log1pf(expf(xr));
    v[u] = sp + bb;
    s += v[u];
  }
  int lane = tid & 63, wv = tid >> 6;
  float ps = s;
#pragma unroll
  for (int d = 1; d < 64; d <<= 1) {
    float o = __shfl_up(ps, d);
    if (lane >= d) ps += o;
  }
  __shared__ float wsum[4];
  if (lane == 63) wsum[wv] = ps;
  __syncthreads();
  float off = 0.f;
  for (int w = 0; w < wv; ++w) off += wsum[w];
  float run = off + ps - s;
#pragma unroll
  for (int u = 0; u < 4; ++u) {
    int t = tid * 4 + u;
    run += v[u];
    Phi[t * NH + h] = Ac * run;
    dts[t * NH + h] = v[u];
  }
}

// -------- fused conv1d+SiLU + chunk-local state:  Sloc[k,h] = sum_s w_s*B_s (x) x_s --------
// block (k,h): computes this chunk's X-tile (conv+silu) in LDS, writes xact for
// ssm_out, then does the 64-dim outer-product accumulation.
__global__ __launch_bounds__(256) void conv_state(const float* __restrict__ proj,
    const float* __restrict__ cw, const float* __restrict__ cb,
    const float* __restrict__ Phi, const float* __restrict__ dts,
    float* __restrict__ xact, float* __restrict__ Sloc) {
  const int k = blockIdx.x, h = blockIdx.y, tid = threadIdx.x;
  __shared__ float Bw[64][68];
  __shared__ float Xs[64][132];
  __shared__ float wS[64];
  const int s0 = k * 64;
  if (tid < 64) {
    float pe = Phi[(s0 + 63) * NH + h];
    float p  = Phi[(s0 + tid) * NH + h];
    wS[tid] = expf(pe + fminf(-p, 80.f)) * dts[(s0 + tid) * NH + h];
  }
  __syncthreads();
  // B staging (weighted)
#pragma unroll
  for (int u = 0; u < 4; ++u) {
    int idx = tid + u * 256, s = idx >> 4, q = (idx & 15) * 4;
    float4 v = *(const float4*)(proj + (size_t)(s0 + s) * NPROJ + OFF_B + h * 64 + q);
    float ws_ = wS[s];
    Bw[s][q + 0] = v.x * ws_; Bw[s][q + 1] = v.y * ws_;
    Bw[s][q + 2] = v.z * ws_; Bw[s][q + 3] = v.w * ws_;
  }
  // conv + silu -> Xs and xact
  {
    int c = tid & 127, th = tid >> 7;
    int cg = h * HDIM + c;
    float w0 = cw[cg * 4 + 0], w1 = cw[cg * 4 + 1], w2 = cw[cg * 4 + 2], w3 = cw[cg * 4 + 3];
    float bias = cb[cg];
    int tb = s0 + th * 32;
    auto P = [&](int t) { return (t >= 0) ? proj[(size_t)t * NPROJ + OFF_X + cg] : 0.f; };
    float x0 = P(tb - 3), x1 = P(tb - 2), x2 = P(tb - 1);
#pragma unroll
    for (int i = 0; i < 32; ++i) {
      float x3 = P(tb + i);
      float a = bias;
      a = fmaf(x0, w0, a); a = fmaf(x1, w1, a); a = fmaf(x2, w2, a); a = fmaf(x3, w3, a);
      float sv = a / (1.f + expf(-a));
      Xs[th * 32 + i][c] = sv;
      xact[(size_t)(tb + i) * DINNER + cg] = sv;
      x0 = x1; x1 = x2; x2 = x3;
    }
  }
  __syncthreads();
  const int d0 = (tid >> 4) * 4, c0 = (tid & 15) * 8;
  float acc[4][8] = {};
#pragma unroll 8
  for (int s = 0; s < 64; ++s) {
    float4 b  = *(const float4*)&Bw[s][d0];
    float4 xa = *(const float4*)&Xs[s][c0];
    float4 xb = *(const float4*)&Xs[s][c0 + 4];
    float bb[4] = {b.x, b.y, b.z, b.w};
    float xx[8] = {xa.x, xa.y, xa.z, xa.w, xb.x, xb.y, xb.z, xb.w};
#pragma unroll
    for (int i = 0; i < 4; ++i)
#pragma unroll
      for (int j = 0; j < 8; ++j) acc[i][j] = fmaf(bb[i], xx[j], acc[i][j]);
  }
  float* dst = Sloc + ((size_t)(k * NH + h) << 13);
#pragma unroll
  for (int i = 0; i < 4; ++i) {
    *(float4*)(dst + (d0 + i) * 128 + c0)     = make_float4(acc[i][0], acc[i][1], acc[i][2], acc[i][3]);
    *(float4*)(dst + (d0 + i) * 128 + c0 + 4) = make_float4(acc[i][4], acc[i][5], acc[i][6], acc[i][7]);
  }
}

// ---------------- sequential scan over 16 chunks (inclusive states) ----------
__global__ __launch_bounds__(256) void chunk_scan(float* __restrict__ Sloc,
    const float* __restrict__ Phi) {
  int b = blockIdx.x;
  int h = b >> 5;
  int e = (b & 31) * 256 + threadIdx.x;
  float run = Sloc[((size_t)h << 13) + e];
#pragma unroll
  for (int k = 1; k < 16; ++k) {
    float lam = expf(Phi[(k * 64 + 63) * NH + h] - Phi[(k * 64 - 1) * NH + h]);
    size_t o = ((size_t)(k * NH + h) << 13) + e;
    run = fmaf(lam, run, Sloc[o]);
    Sloc[o] = run;
  }
}

// ---------------- per-chunk output: diag quadratic + carried state + Dp*x ----
__global__ __launch_bounds__(256) void ssm_out(const float* __restrict__ proj,
    const float* __restrict__ xact, const float* __restrict__ Phi,
    const float* __restrict__ dts, const float* __restrict__ Dp,
    const float* __restrict__ Sloc, float* __restrict__ y) {
  const int k = blockIdx.x, h = blockIdx.y, zh = blockIdx.z, tid = threadIdx.x;
  __shared__ float Cst[64][68];   // [d][t]
  __shared__ float Bst[64][68];   // [d][s]; later masked S[t][s]
  __shared__ float Xs[64][68];    // [s][c]; later Sprev[d][c]
  __shared__ float phiT[64], eS[64], dS[64], eT[64];
  const int t0 = k * 64;
  const int ty = tid >> 4, tx = tid & 15, ri = ty * 4, cj = tx * 4;

#pragma unroll
  for (int u = 0; u < 4; ++u) {
    int idx = tid + u * 256, i = idx >> 4, fq = (idx & 15) * 4;
    float4 cv = *(const float4*)(proj + (size_t)(t0 + i) * NPROJ + OFF_C + h * 64 + fq);
    Cst[fq + 0][i] = cv.x; Cst[fq + 1][i] = cv.y; Cst[fq + 2][i] = cv.z; Cst[fq + 3][i] = cv.w;
    float4 bv = *(const float4*)(proj + (size_t)(t0 + i) * NPROJ + OFF_B + h * 64 + fq);
    Bst[fq + 0][i] = bv.x; Bst[fq + 1][i] = bv.y; Bst[fq + 2][i] = bv.z; Bst[fq + 3][i] = bv.w;
    float4 xv = *(const float4*)(xact + (size_t)(t0 + i) * DINNER + h * HDIM + zh * 64 + fq);
    *(float4*)&Xs[i][fq] = xv;
  }
  if (tid < 64) {
    float p = Phi[(t0 + tid) * NH + h];
    phiT[tid] = p;
    eS[tid] = fminf(-p, 80.f);
    dS[tid] = dts[(t0 + tid) * NH + h];
    eT[tid] = (k > 0) ? expf(p - Phi[(t0 - 1) * NH + h]) : 0.f;
  }
  __syncthreads();

  float sreg[4][4] = {};
#pragma unroll 16
  for (int d = 0; d < 64; ++d) {
    float4 cv = *(const float4*)&Cst[d][ri];
    float4 bv = *(const float4*)&Bst[d][cj];
    float a[4] = {cv.x, cv.y, cv.z, cv.w};
    float b[4] = {bv.x, bv.y, bv.z, bv.w};
#pragma unroll
    for (int i = 0; i < 4; ++i)
#pragma unroll
      for (int j = 0; j < 4; ++j) sreg[i][j] = fmaf(a[i], b[j], sreg[i][j]);
  }
  __syncthreads();
#pragma unroll
  for (int i = 0; i < 4; ++i) {
    int ti = ri + i;
#pragma unroll
    for (int j = 0; j < 4; ++j) {
      int sj = cj + j;
      float f = (sj <= ti) ? expf(phiT[ti] + eS[sj]) * dS[sj] : 0.f;
      Bst[ti][sj] = sreg[i][j] * f;
    }
  }
  __syncthreads();

  float acc[4][4] = {};
#pragma unroll 8
  for (int j = 0; j < 64; j += 4) {
    float4 x0 = *(const float4*)&Xs[j + 0][cj];
    float4 x1 = *(const float4*)&Xs[j + 1][cj];
    float4 x2 = *(const float4*)&Xs[j + 2][cj];
    float4 x3 = *(const float4*)&Xs[j + 3][cj];
    float X0[4] = {x0.x, x0.y, x0.z, x0.w};
    float X1[4] = {x1.x, x1.y, x1.z, x1.w};
    float X2[4] = {x2.x, x2.y, x2.z, x2.w};
    float X3[4] = {x3.x, x3.y, x3.z, x3.w};
#pragma unroll
    for (int i = 0; i < 4; ++i) {
      float4 sv = *(const float4*)&Bst[ri + i][j];
#pragma unroll
      for (int c = 0; c < 4; ++c) {
        acc[i][c] = fmaf(sv.x, X0[c], acc[i][c]);
        acc[i][c] = fmaf(sv.y, X1[c], acc[i][c]);
        acc[i][c] = fmaf(sv.z, X2[c], acc[i][c]);
        acc[i][c] = fmaf(sv.w, X3[c], acc[i][c]);
      }
    }
  }
  float dp = Dp[h];
#pragma unroll
  for (int i = 0; i < 4; ++i)
#pragma unroll
    for (int j = 0; j < 4; ++j) acc[i][j] = fmaf(dp, Xs[ri + i][cj + j], acc[i][j]);

  if (k > 0) {
    __syncthreads();
#pragma unroll
    for (int u = 0; u < 4; ++u) {
      int idx = tid + u * 256, d = idx >> 4, q = (idx & 15) * 4;
      *(float4*)&Xs[d][q] =
          *(const float4*)(Sloc + ((size_t)((k - 1) * NH + h) << 13) + d * 128 + zh * 64 + q);
    }
    __syncthreads();
    float a2[4][4] = {};
#pragma unroll 16
    for (int d = 0; d < 64; ++d) {
      float4 cv = *(const float4*)&Cst[d][ri];
      float4 sv = *(const float4*)&Xs[d][cj];
      float a[4] = {cv.x, cv.y, cv.z, cv.w};
      float b[4] = {sv.x, sv.y, sv.z, sv.w};
#pragma unroll
      for (int i = 0; i < 4; ++i)
#pragma unroll
        for (int j = 0; j < 4; ++j) a2[i][j] = fmaf(a[i], b[j], a2[i][j]);
    }
#pragma unroll
    for (int i = 0; i < 4; ++i)
#pragma unroll
      for (int j = 0; j < 4; ++j) acc[i][j] = fmaf(eT[ri + i], a2[i][j], acc[i][j]);
  }
#pragma unroll
  for (int i = 0; i < 4; ++i)
    *(float4*)(y + (size_t)(t0 + ri + i) * DINNER + h * HDIM + zh * 64 + cj) =
        make_float4(acc[i][0], acc[i][1], acc[i][2], acc[i][3]);
}

// ---------------- RMSNorm + gate -> single bf16 plane ----------------
__global__ __launch_bounds__(256) void norm_gate(const float* __restrict__ y,
    const float* __restrict__ proj, const float* __restrict__ nw,
    u16* __restrict__ yh) {
  int t = blockIdx.x, tid = threadIdx.x;
  float v[6], ss = 0.f;
#pragma unroll
  for (int k = 0; k < 6; ++k) {
    v[k] = y[(size_t)t * DINNER + tid + k * 256];
    ss = fmaf(v[k], v[k], ss);
  }
#pragma unroll
  for (int d = 1; d < 64; d <<= 1) ss += __shfl_xor(ss, d);
  __shared__ float wsum[4];
  int wv = tid >> 6;
  if ((tid & 63) == 0) wsum[wv] = ss;
  __syncthreads();
  float tot = wsum[0] + wsum[1] + wsum[2] + wsum[3];
  float rms = rsqrtf(tot / 1536.f + 1e-5f);
#pragma unroll
  for (int k = 0; k < 6; ++k) {
    int c = tid + k * 256;
    float z = proj[(size_t)t * NPROJ + OFF_Z + c];
    float sz = z / (1.f + expf(-z));
    yh[(size_t)t * DINNER + c] = f2b(v[k] * rms * nw[c] * sz);
  }
}

extern "C" void kernel_launch(void* const* d_in, const int* in_sizes, int n_in,
                              void* d_out, int out_size, void* d_ws, size_t ws_size,
                              hipStream_t stream) {
  const float* x       = (const float*)d_in[0];
  const float* W_in    = (const float*)d_in[1];
  const float* conv_w  = (const float*)d_in[2];
  const float* conv_b  = (const float*)d_in[3];
  const float* A_log   = (const float*)d_in[4];
  const float* Dp      = (const float*)d_in[5];
  const float* dt_bias = (const float*)d_in[6];
  const float* W_out   = (const float*)d_in[7];
  const float* norm_w  = (const float*)d_in[8];
  float* out = (float*)d_out;

  char* base = (char*)d_ws;
  size_t o = 0;
  auto alloc = [&](size_t bytes) { char* r = base + o; o += (bytes + 255) & ~(size_t)255; return r; };
  float* proj = (float*)alloc((size_t)LSEQ * NPROJ * 4);
  float* xact = (float*)alloc((size_t)LSEQ * DINNER * 4);
  float* ybuf = (float*)alloc((size_t)LSEQ * DINNER * 4);
  float* Phi  = (float*)alloc((size_t)LSEQ * NH * 4);
  float* dtsb = (float*)alloc((size_t)LSEQ * NH * 4);
  float* Sloc = (float*)alloc((size_t)16 * NH * 64 * 128 * 4);
  u16* Ah  = (u16*)alloc((size_t)LSEQ * 768 * 2);
  u16* Wh  = (u16*)alloc((size_t)NPADW * 768 * 2);
  u16* Woh = (u16*)alloc((size_t)768 * DINNER * 2);
  u16* Yh  = (u16*)alloc((size_t)LSEQ * DINNER * 2);
  float* Pp = proj;   // out-proj partials alias proj (dead by then): 4*1024*768*4 = 12.6MB

  // split to bf16 planes (single-plane everywhere)
  ksplit_all<<<dim3((S0N + S1N + S2N) / 256), 256, 0, stream>>>(
      x, W_in, W_out, Ah, Wh, Woh);
  // in-projection: 64x128 tiles, BK=64, XCD-striped, 640 blocks
  gemm1<64, 128, 0, true><<<dim3(640), 256, 0, stream>>>(
      Ah, Wh, proj, 768, 768, 768, NPROJ, NPROJ);
  // dt & Phi
  dtphi<<<dim3(NH), 256, 0, stream>>>(proj, A_log, dt_bias, Phi, dtsb);
  // fused conv+silu + chunk state
  conv_state<<<dim3(16, NH), 256, 0, stream>>>(proj, conv_w, conv_b, Phi, dtsb, xact, Sloc);
  chunk_scan<<<dim3(NH * 32), 256, 0, stream>>>(Sloc, Phi);
  ssm_out<<<dim3(16, NH, 2), 256, 0, stream>>>(proj, xact, Phi, dtsb, Dp, Sloc, ybuf);
  // norm + gate -> bf16
  norm_gate<<<dim3(LSEQ), 256, 0, stream>>>(ybuf, proj, norm_w, Yh);
  // out-projection: split-K=4, 64x64 tiles, BK=64, 768 blocks -> partials
  gemm1<64, 64, 1, false><<<dim3(768), 256, 0, stream>>>(
      Yh, Woh, Pp, 1536, 1536, 384, 768, 768);
  // reduce partials
  addk<<<dim3(LSEQ * 768 / 4 / 256), 256, 0, stream>>>(Pp, out);
}

// Round 7
// 72.251 us; speedup vs baseline: 1.2998x; 1.2998x over previous
//
#include <hip/hip_runtime.h>
#include <cmath>

#define LSEQ   1024
#define NPROJ  4620
#define NPADW  4736
#define DINNER 1536
#define NH     12
#define HDIM   128
#define OFF_Z  0
#define OFF_X  1536
#define OFF_B  3072
#define OFF_C  3840
#define OFF_DT 4608

typedef unsigned short u16;
typedef unsigned int u32;
typedef short bf16x8 __attribute__((ext_vector_type(8)));
typedef float f32x4 __attribute__((ext_vector_type(4)));

__device__ inline u16 f2b(float f) {            // f32 -> bf16 RNE
  unsigned u = __float_as_uint(f);
  return (u16)((u + 0x7fffu + ((u >> 16) & 1u)) >> 16);
}
__device__ inline float b2f(u16 h) { return __uint_as_float(((unsigned)h) << 16); }
__device__ inline u32 pk2(float a, float b) { return (u32)f2b(a) | ((u32)f2b(b) << 16); }

__device__ inline void gll16(const void* g, void* l) {
  __builtin_amdgcn_global_load_lds((const __attribute__((address_space(1))) void*)g,
                                   (__attribute__((address_space(3))) void*)l, 16, 0, 0);
}

// ---------- split to single bf16 planes: x -> Ah, W_in -> Wh (padded), W_out -> Woh ----
#define S0N 196608              // 1024*768/4
#define S1N 909312              // 4736*768/4 (valid 887040)
#define S1V 887040
#define S2N 294912              // 768*1536/4
__global__ __launch_bounds__(256) void ksplit_all(const float* __restrict__ x,
    const float* __restrict__ Wi, const float* __restrict__ Wo,
    u16* __restrict__ Ah, u16* __restrict__ Wh, u16* __restrict__ Woh) {
  int i = blockIdx.x * 256 + threadIdx.x;
  const float* src; u16* hi; int j, valid;
  if (i < S0N)            { src = x;  hi = Ah;  j = i;              valid = S0N; }
  else if (i < S0N + S1N) { src = Wi; hi = Wh;  j = i - S0N;        valid = S1V; }
  else                    { src = Wo; hi = Woh; j = i - S0N - S1N;  valid = S2N; }
  float4 v = (j < valid) ? ((const float4*)src)[j] : make_float4(0.f, 0.f, 0.f, 0.f);
  ((uint2*)hi)[j] = make_uint2(pk2(v.x, v.y), pk2(v.z, v.w));
}

// ---------- pure-bf16 MFMA GEMM: C = A[M,K] * W[N,K]^T (R5/R6-proven structure) ----------
template<int BM, int BN, int MAP, bool NG>
__global__ __launch_bounds__(256) void gemm1(const u16* __restrict__ Ah,
    const u16* __restrict__ Wh, float* __restrict__ C,
    int lda, int ldw, int Ksl, int Nreal, int ldc) {
  constexpr int PLA = BM * 64;
  constexpr int IA = BM / 8, IW = BN / 8, ITOT = IA + IW;
  constexpr int FRn = BN / 32;
  __shared__ u16 lds[PLA + BN * 64];
  const int tid = threadIdx.x;
  const int l = tid & 63, w = tid >> 6;
  const int wm = w >> 1, wn = w & 1;
  const int kg = l >> 4, li = l & 15;

  int b = blockIdx.x, m0, n0, koff;
  float* Cp = C;
  if (MAP == 0) {                 // in-proj: 8 xcd * (5 colblk(128) x 16 rowblk(64))
    int xcd = b & 7, idx = b >> 3;
    m0 = (idx & 15) * 64;
    n0 = (xcd * 5 + (idx >> 4)) * 128;
    koff = 0;
    if (NG && n0 >= NPADW) return;
  } else {                        // out-proj: split-K=4; 8 xcd * (6 grp x 16 rowblk)
    int xcd = b & 7, idx = b >> 3;
    int gg = xcd * 6 + (idx >> 4);
    m0 = (idx & 15) * 64;
    n0 = (gg % 12) * 64;
    koff = (gg / 12) * 384;
    Cp = C + (size_t)(gg / 12) * LSEQ * ldc;
  }

  const int srcg = ((l & 7) ^ (l >> 3)) * 8;
  auto stage = [&](int t) {
    const int k0 = koff + t * 64;
    for (int q = w; q < ITOT; q += 4) {
      const u16* gb; int r0b, ldk, dst;
      if (q < IA) { gb = Ah; r0b = m0 + 8 * q;        dst = 8 * q * 64;              ldk = lda; }
      else        { gb = Wh; r0b = n0 + 8 * (q - IA); dst = PLA + 8 * (q - IA) * 64; ldk = ldw; }
      gll16(gb + (size_t)(r0b + (l >> 3)) * ldk + k0 + srcg, &lds[dst]);
    }
  };
  auto rd = [&](int region, int row, int ks) -> bf16x8 {
    return *(const bf16x8*)&lds[region + row * 64 + (((ks * 4 + kg) ^ (row & 7)) << 3)];
  };

  f32x4 acc[2][FRn];
#pragma unroll
  for (int m = 0; m < 2; ++m)
#pragma unroll
    for (int n = 0; n < FRn; ++n) acc[m][n] = (f32x4){0.f, 0.f, 0.f, 0.f};

  const int NT = Ksl / 64;
  stage(0);
  asm volatile("s_waitcnt vmcnt(0)" ::: "memory");
  __syncthreads();
  for (int t = 0; t < NT; ++t) {
    bf16x8 af[2][2], wf[FRn][2];
#pragma unroll
    for (int ks = 0; ks < 2; ++ks) {
#pragma unroll
      for (int m = 0; m < 2; ++m)
        af[m][ks] = rd(0, wm * 32 + m * 16 + li, ks);
#pragma unroll
      for (int n = 0; n < FRn; ++n)
        wf[n][ks] = rd(PLA, wn * (BN / 2) + n * 16 + li, ks);
    }
    __syncthreads();
    if (t + 1 < NT) stage(t + 1);
#pragma unroll
    for (int ks = 0; ks < 2; ++ks)
#pragma unroll
      for (int m = 0; m < 2; ++m)
#pragma unroll
        for (int n = 0; n < FRn; ++n)
          acc[m][n] = __builtin_amdgcn_mfma_f32_16x16x32_bf16(af[m][ks], wf[n][ks], acc[m][n], 0, 0, 0);
    if (t + 1 < NT) {
      asm volatile("s_waitcnt vmcnt(0)" ::: "memory");
      __syncthreads();
    }
  }
#pragma unroll
  for (int m = 0; m < 2; ++m) {
    int rbase = m0 + wm * 32 + m * 16 + kg * 4;
#pragma unroll
    for (int n = 0; n < FRn; ++n) {
      int col = n0 + wn * (BN / 2) + n * 16 + li;
      if (!NG || col < Nreal) {
#pragma unroll
        for (int r = 0; r < 4; ++r)
          Cp[(size_t)(rbase + r) * ldc + col] = acc[m][n][r];
      }
    }
  }
}

// ---------------- out = P0+P1+P2+P3 (split-K reduce) ----------------
__global__ __launch_bounds__(256) void addk(const float* __restrict__ P,
    float* __restrict__ out) {
  const int S = LSEQ * 768 / 4;
  int i = blockIdx.x * 256 + threadIdx.x;
  float4 a = ((const float4*)P)[i];
  float4 b = ((const float4*)P)[i + S];
  float4 c = ((const float4*)P)[i + 2 * S];
  float4 d = ((const float4*)P)[i + 3 * S];
  ((float4*)out)[i] = make_float4(a.x + b.x + c.x + d.x, a.y + b.y + c.y + d.y,
                                  a.z + b.z + c.z + d.z, a.w + b.w + c.w + d.w);
}

// ---------------- dt = softplus(dt_r)+bias ; Phi = cumsum(A*dt) --------------
__global__ __launch_bounds__(256) void dtphi(const float* __restrict__ proj,
    const float* __restrict__ A_log, const float* __restrict__ dt_bias,
    float* __restrict__ Phi, float* __restrict__ dts) {
  int h = blockIdx.x, tid = threadIdx.x;
  float Ac = -expf(A_log[h]);
  float bb = dt_bias[h];
  float v[4], s = 0.f;
#pragma unroll
  for (int u = 0; u < 4; ++u) {
    int t = tid * 4 + u;
    float xr = proj[(size_t)t * NPROJ + OFF_DT + h];
    float sp = (xr > 20.f) ? xr : log1pf(expf(xr));
    v[u] = sp + bb;
    s += v[u];
  }
  int lane = tid & 63, wv = tid >> 6;
  float ps = s;
#pragma unroll
  for (int d = 1; d < 64; d <<= 1) {
    float o = __shfl_up(ps, d);
    if (lane >= d) ps += o;
  }
  __shared__ float wsum[4];
  if (lane == 63) wsum[wv] = ps;
  __syncthreads();
  float off = 0.f;
  for (int w = 0; w < wv; ++w) off += wsum[w];
  float run = off + ps - s;
#pragma unroll
  for (int u = 0; u < 4; ++u) {
    int t = tid * 4 + u;
    run += v[u];
    Phi[t * NH + h] = Ac * run;
    dts[t * NH + h] = v[u];
  }
}

// -------- fused conv1d+SiLU + chunk-state via MFMA --------
// block (k,h): X^T[c][s] (bf16, LDS+global), Bw[d][s]=wS[s]*B[s][d] (bf16),
// then H^T[c][d] = Xt · Bw^T via MFMA -> SlocF (f32, [c][d] layout).
__global__ __launch_bounds__(256) void conv_state(const float* __restrict__ proj,
    const float* __restrict__ cw, const float* __restrict__ cb,
    const float* __restrict__ Phi, const float* __restrict__ dts,
    u16* __restrict__ xactT, float* __restrict__ SlocF) {
  const int k = blockIdx.x, h = blockIdx.y, tid = threadIdx.x;
  const int l = tid & 63, w = tid >> 6, kg = l >> 4, li = l & 15;
  __shared__ u16 Bw[64 * 64];
  __shared__ u16 Xt[128 * 64];
  __shared__ float wS[64];
  const int s0 = k * 64;
  if (tid < 64) {
    float pe = Phi[(s0 + 63) * NH + h];
    float p  = Phi[(s0 + tid) * NH + h];
    wS[tid] = expf(pe + fminf(-p, 80.f)) * dts[(s0 + tid) * NH + h];
  }
  __syncthreads();
  // Bw[d][s] staging (weighted, swizzled bf16)
#pragma unroll
  for (int u = 0; u < 4; ++u) {
    int idx = tid + u * 256, s = idx >> 4, q = (idx & 15) * 4;
    float4 v = *(const float4*)(proj + (size_t)(s0 + s) * NPROJ + OFF_B + h * 64 + q);
    float ws_ = wS[s];
    float vv[4] = {v.x, v.y, v.z, v.w};
#pragma unroll
    for (int j = 0; j < 4; ++j) {
      int d = q + j;
      Bw[d * 64 + (((s >> 3) ^ (d & 7)) << 3) + (s & 7)] = f2b(vv[j] * ws_);
    }
  }
  // conv + silu -> Xt[c][s] (swizzled LDS) + xactT (linear global)
  {
    int c = tid & 127, th = tid >> 7;
    int cg = h * HDIM + c;
    float w0 = cw[cg * 4], w1 = cw[cg * 4 + 1], w2 = cw[cg * 4 + 2], w3 = cw[cg * 4 + 3];
    float bias = cb[cg];
    int tb = s0 + th * 32;
    auto P = [&](int t) { return (t >= 0) ? proj[(size_t)t * NPROJ + OFF_X + cg] : 0.f; };
    float x0 = P(tb - 3), x1 = P(tb - 2), x2 = P(tb - 1);
    u32 pkb[16];
    float prev = 0.f;
#pragma unroll
    for (int i = 0; i < 32; ++i) {
      float x3 = P(tb + i);
      float a = bias;
      a = fmaf(x0, w0, a); a = fmaf(x1, w1, a); a = fmaf(x2, w2, a); a = fmaf(x3, w3, a);
      float sv = a / (1.f + expf(-a));
      if (i & 1) pkb[i >> 1] = pk2(prev, sv); else prev = sv;
      x0 = x1; x1 = x2; x2 = x3;
    }
#pragma unroll
    for (int g = 0; g < 4; ++g) {
      int sg = th * 4 + g;
      *(uint4*)&Xt[c * 64 + ((sg ^ (c & 7)) << 3)] =
          make_uint4(pkb[g * 4], pkb[g * 4 + 1], pkb[g * 4 + 2], pkb[g * 4 + 3]);
    }
    size_t xo = ((size_t)(k * NH + h) * 128 + c) * 64 + th * 32;
#pragma unroll
    for (int g = 0; g < 4; ++g)
      *(uint4*)(xactT + xo + g * 8) =
          make_uint4(pkb[g * 4], pkb[g * 4 + 1], pkb[g * 4 + 2], pkb[g * 4 + 3]);
  }
  __syncthreads();
  // H^T[c][d] = sum_s Xt[c][s] * Bw[d][s]   (MFMA, M=128c x N=64d x K=64s)
  const int wm = w >> 1, wn = w & 1;
  auto rd = [&](const u16* reg, int row, int ks) -> bf16x8 {
    return *(const bf16x8*)&reg[row * 64 + (((ks * 4 + kg) ^ (row & 7)) << 3)];
  };
  f32x4 acc[4][2];
#pragma unroll
  for (int m = 0; m < 4; ++m)
#pragma unroll
    for (int n = 0; n < 2; ++n) acc[m][n] = (f32x4){0.f, 0.f, 0.f, 0.f};
#pragma unroll
  for (int ks = 0; ks < 2; ++ks) {
    bf16x8 xf[4], bf[2];
#pragma unroll
    for (int m = 0; m < 4; ++m) xf[m] = rd(Xt, wm * 64 + m * 16 + li, ks);
#pragma unroll
    for (int n = 0; n < 2; ++n) bf[n] = rd(Bw, wn * 32 + n * 16 + li, ks);
#pragma unroll
    for (int m = 0; m < 4; ++m)
#pragma unroll
      for (int n = 0; n < 2; ++n)
        acc[m][n] = __builtin_amdgcn_mfma_f32_16x16x32_bf16(xf[m], bf[n], acc[m][n], 0, 0, 0);
  }
  float* dst = SlocF + ((size_t)(k * NH + h) << 13);
#pragma unroll
  for (int m = 0; m < 4; ++m)
#pragma unroll
    for (int n = 0; n < 2; ++n)
#pragma unroll
      for (int r = 0; r < 4; ++r) {
        int c = wm * 64 + m * 16 + kg * 4 + r;
        int d = wn * 32 + n * 16 + li;
        dst[c * 64 + d] = acc[m][n][r];
      }
}

// ------- sequential scan over 16 chunks; emits inclusive states as bf16 [c][d] -------
__global__ __launch_bounds__(256) void chunk_scan(const float* __restrict__ SlocF,
    u16* __restrict__ SlocT, const float* __restrict__ Phi) {
  int b = blockIdx.x;
  int h = b >> 5;
  int e = (b & 31) * 256 + threadIdx.x;
  float run = SlocF[((size_t)h << 13) + e];
  SlocT[((size_t)h << 13) + e] = f2b(run);
#pragma unroll
  for (int k = 1; k < 16; ++k) {
    float lam = expf(Phi[(k * 64 + 63) * NH + h] - Phi[(k * 64 - 1) * NH + h]);
    size_t o = ((size_t)(k * NH + h) << 13) + e;
    run = fmaf(lam, run, SlocF[o]);
    SlocT[o] = f2b(run);
  }
}

// ------- per-chunk output via 3 MFMA GEMMs: S=C·B^T, Y=P·X + eT*(C·Sprev^T) + Dp*x -------
__global__ __launch_bounds__(256) void ssm_out(const float* __restrict__ proj,
    const u16* __restrict__ xactT, const float* __restrict__ Phi,
    const float* __restrict__ dts, const float* __restrict__ Dp,
    const u16* __restrict__ SlocT, u16* __restrict__ ybuf) {
  const int k = blockIdx.x, h = blockIdx.y, zh = blockIdx.z, tid = threadIdx.x;
  const int l = tid & 63, w = tid >> 6, kg = l >> 4, li = l & 15;
  const int wm = w >> 1, wn = w & 1;
  __shared__ u16 Cs[4096], Bs[4096], Ps[4096], Xs[4096], Ss[4096];
  __shared__ float phiT[64], eSs[64], dSs[64], eTs[64];
  const int t0 = k * 64;
  const int srcg = ((l & 7) ^ (l >> 3)) * 8;
  // async-stage Xt (and SprevT) rows: 8 rows / gll16, 2 per wave per tensor
  {
    const u16* xsrc = xactT + ((size_t)(k * NH + h) * 128 + zh * 64) * 64;
#pragma unroll
    for (int j = 0; j < 2; ++j) {
      int rb = w * 16 + j * 8;
      gll16(xsrc + (size_t)(rb + (l >> 3)) * 64 + srcg, &Xs[rb * 64]);
    }
    if (k > 0) {
      const u16* ssrc = SlocT + (((size_t)((k - 1) * NH + h)) << 13) + (size_t)(zh * 64) * 64;
#pragma unroll
      for (int j = 0; j < 2; ++j) {
        int rb = w * 16 + j * 8;
        gll16(ssrc + (size_t)(rb + (l >> 3)) * 64 + srcg, &Ss[rb * 64]);
      }
    }
  }
  // C,B cvt-staging (f32 -> bf16, swizzled)
#pragma unroll
  for (int u = 0; u < 4; ++u) {
    int idx = tid + u * 256, i = idx >> 4, q = (idx & 15) * 4;
    int aoff = i * 64 + (((q >> 3) ^ (i & 7)) << 3) + (q & 4);
    float4 cv = *(const float4*)(proj + (size_t)(t0 + i) * NPROJ + OFF_C + h * 64 + q);
    float4 bv = *(const float4*)(proj + (size_t)(t0 + i) * NPROJ + OFF_B + h * 64 + q);
    *(uint2*)&Cs[aoff] = make_uint2(pk2(cv.x, cv.y), pk2(cv.z, cv.w));
    *(uint2*)&Bs[aoff] = make_uint2(pk2(bv.x, bv.y), pk2(bv.z, bv.w));
  }
  if (tid < 64) {
    float p = Phi[(t0 + tid) * NH + h];
    phiT[tid] = p;
    eSs[tid] = fminf(-p, 80.f);
    dSs[tid] = dts[(t0 + tid) * NH + h];
    eTs[tid] = (k > 0) ? expf(p - Phi[(t0 - 1) * NH + h]) : 0.f;
  }
  __syncthreads();
  auto rd = [&](const u16* reg, int row, int ks) -> bf16x8 {
    return *(const bf16x8*)&reg[row * 64 + (((ks * 4 + kg) ^ (row & 7)) << 3)];
  };
  // GEMM1: S[t][s] = sum_d C[t][d] B[s][d]
  bf16x8 Cf[2][2];
  f32x4 accS[2][2];
#pragma unroll
  for (int m = 0; m < 2; ++m)
#pragma unroll
    for (int n = 0; n < 2; ++n) accS[m][n] = (f32x4){0.f, 0.f, 0.f, 0.f};
#pragma unroll
  for (int ks = 0; ks < 2; ++ks) {
    bf16x8 Bf[2];
#pragma unroll
    for (int m = 0; m < 2; ++m) Cf[m][ks] = rd(Cs, wm * 32 + m * 16 + li, ks);
#pragma unroll
    for (int n = 0; n < 2; ++n) Bf[n] = rd(Bs, wn * 32 + n * 16 + li, ks);
#pragma unroll
    for (int m = 0; m < 2; ++m)
#pragma unroll
      for (int n = 0; n < 2; ++n)
        accS[m][n] = __builtin_amdgcn_mfma_f32_16x16x32_bf16(Cf[m][ks], Bf[n], accS[m][n], 0, 0, 0);
  }
  // mask + exp -> P (bf16, swizzled)
#pragma unroll
  for (int m = 0; m < 2; ++m)
#pragma unroll
    for (int n = 0; n < 2; ++n)
#pragma unroll
      for (int r = 0; r < 4; ++r) {
        int t = wm * 32 + m * 16 + kg * 4 + r;
        int s = wn * 32 + n * 16 + li;
        float f = (s <= t) ? expf(phiT[t] + eSs[s]) * dSs[s] : 0.f;
        Ps[t * 64 + (((s >> 3) ^ (t & 7)) << 3) + (s & 7)] = f2b(accS[m][n][r] * f);
      }
  __syncthreads();
  // GEMM2: Y = P·X  ;  GEMM3: Y2 = C·Sprev^T
  f32x4 accY[2][2], acc2[2][2];
#pragma unroll
  for (int m = 0; m < 2; ++m)
#pragma unroll
    for (int n = 0; n < 2; ++n) {
      accY[m][n] = (f32x4){0.f, 0.f, 0.f, 0.f};
      acc2[m][n] = (f32x4){0.f, 0.f, 0.f, 0.f};
    }
#pragma unroll
  for (int ks = 0; ks < 2; ++ks) {
    bf16x8 Pf[2], Xf[2];
#pragma unroll
    for (int m = 0; m < 2; ++m) Pf[m] = rd(Ps, wm * 32 + m * 16 + li, ks);
#pragma unroll
    for (int n = 0; n < 2; ++n) Xf[n] = rd(Xs, wn * 32 + n * 16 + li, ks);
#pragma unroll
    for (int m = 0; m < 2; ++m)
#pragma unroll
      for (int n = 0; n < 2; ++n)
        accY[m][n] = __builtin_amdgcn_mfma_f32_16x16x32_bf16(Pf[m], Xf[n], accY[m][n], 0, 0, 0);
    if (k > 0) {
      bf16x8 Sf[2];
#pragma unroll
      for (int n = 0; n < 2; ++n) Sf[n] = rd(Ss, wn * 32 + n * 16 + li, ks);
#pragma unroll
      for (int m = 0; m < 2; ++m)
#pragma unroll
        for (int n = 0; n < 2; ++n)
          acc2[m][n] = __builtin_amdgcn_mfma_f32_16x16x32_bf16(Cf[m][ks], Sf[n], acc2[m][n], 0, 0, 0);
    }
  }
  float dp = Dp[h];
#pragma unroll
  for (int m = 0; m < 2; ++m)
#pragma unroll
    for (int n = 0; n < 2; ++n)
#pragma unroll
      for (int r = 0; r < 4; ++r) {
        int t = wm * 32 + m * 16 + kg * 4 + r;
        int c = wn * 32 + n * 16 + li;
        float xv = b2f(Xs[c * 64 + (((t >> 3) ^ (c & 7)) << 3) + (t & 7)]);
        float val = accY[m][n][r] + eTs[t] * acc2[m][n][r] + dp * xv;
        ybuf[(size_t)(t0 + t) * DINNER + h * HDIM + zh * 64 + c] = f2b(val);
      }
}

// ---------------- RMSNorm + gate (reads bf16 y) -> bf16 Yh ----------------
__global__ __launch_bounds__(256) void norm_gate(const u16* __restrict__ y,
    const float* __restrict__ proj, const float* __restrict__ nw,
    u16* __restrict__ yh) {
  int t = blockIdx.x, tid = threadIdx.x;
  float v[6], ss = 0.f;
#pragma unroll
  for (int k = 0; k < 6; ++k) {
    v[k] = b2f(y[(size_t)t * DINNER + tid + k * 256]);
    ss = fmaf(v[k], v[k], ss);
  }
#pragma unroll
  for (int d = 1; d < 64; d <<= 1) ss += __shfl_xor(ss, d);
  __shared__ float wsum[4];
  int wv = tid >> 6;
  if ((tid & 63) == 0) wsum[wv] = ss;
  __syncthreads();
  float tot = wsum[0] + wsum[1] + wsum[2] + wsum[3];
  float rms = rsqrtf(tot / 1536.f + 1e-5f);
#pragma unroll
  for (int k = 0; k < 6; ++k) {
    int c = tid + k * 256;
    float z = proj[(size_t)t * NPROJ + OFF_Z + c];
    float sz = z / (1.f + expf(-z));
    yh[(size_t)t * DINNER + c] = f2b(v[k] * rms * nw[c] * sz);
  }
}

extern "C" void kernel_launch(void* const* d_in, const int* in_sizes, int n_in,
                              void* d_out, int out_size, void* d_ws, size_t ws_size,
                              hipStream_t stream) {
  const float* x       = (const float*)d_in[0];
  const float* W_in    = (const float*)d_in[1];
  const float* conv_w  = (const float*)d_in[2];
  const float* conv_b  = (const float*)d_in[3];
  const float* A_log   = (const float*)d_in[4];
  const float* Dp      = (const float*)d_in[5];
  const float* dt_bias = (const float*)d_in[6];
  const float* W_out   = (const float*)d_in[7];
  const float* norm_w  = (const float*)d_in[8];
  float* out = (float*)d_out;

  char* base = (char*)d_ws;
  size_t o = 0;
  auto alloc = [&](size_t bytes) { char* r = base + o; o += (bytes + 255) & ~(size_t)255; return r; };
  float* proj  = (float*)alloc((size_t)LSEQ * NPROJ * 4);
  u16*   ybuf  = (u16*)alloc((size_t)LSEQ * DINNER * 2);
  float* Phi   = (float*)alloc((size_t)LSEQ * NH * 4);
  float* dtsb  = (float*)alloc((size_t)LSEQ * NH * 4);
  float* SlocF = (float*)alloc((size_t)16 * NH * 8192 * 4);
  u16*   SlocT = (u16*)alloc((size_t)16 * NH * 8192 * 2);
  u16*   xactT = (u16*)alloc((size_t)16 * NH * 128 * 64 * 2);
  u16* Ah  = (u16*)alloc((size_t)LSEQ * 768 * 2);
  u16* Wh  = (u16*)alloc((size_t)NPADW * 768 * 2);
  u16* Woh = (u16*)alloc((size_t)768 * DINNER * 2);
  u16* Yh  = (u16*)alloc((size_t)LSEQ * DINNER * 2);
  float* Pp = proj;   // out-proj partials alias proj (dead by then)

  ksplit_all<<<dim3((S0N + S1N + S2N) / 256), 256, 0, stream>>>(
      x, W_in, W_out, Ah, Wh, Woh);
  gemm1<64, 128, 0, true><<<dim3(640), 256, 0, stream>>>(
      Ah, Wh, proj, 768, 768, 768, NPROJ, NPROJ);
  dtphi<<<dim3(NH), 256, 0, stream>>>(proj, A_log, dt_bias, Phi, dtsb);
  conv_state<<<dim3(16, NH), 256, 0, stream>>>(proj, conv_w, conv_b, Phi, dtsb, xactT, SlocF);
  chunk_scan<<<dim3(NH * 32), 256, 0, stream>>>(SlocF, SlocT, Phi);
  ssm_out<<<dim3(16, NH, 2), 256, 0, stream>>>(proj, xactT, Phi, dtsb, Dp, SlocT, ybuf);
  norm_gate<<<dim3(LSEQ), 256, 0, stream>>>(ybuf, proj, norm_w, Yh);
  gemm1<64, 64, 1, false><<<dim3(768), 256, 0, stream>>>(
      Yh, Woh, Pp, 1536, 1536, 384, 768, 768);
  addk<<<dim3(LSEQ * 768 / 4 / 256), 256, 0, stream>>>(Pp, out);
}